// Round 10
// baseline (442.564 us; speedup 1.0000x reference)
//
#include <hip/hip_runtime.h>
#include <math.h>

#define NNODES 50000
#define NEDGES 800000
#define INDIM 256
#define HID 64
#define HEADS 4
#define OUTDIM 64
#define NEG_SLOPE 0.2f
#define NB ((NNODES + 1023) / 1024)   // 49 scan blocks

typedef __attribute__((ext_vector_type(4))) float f32x4;
typedef _Float16 __attribute__((ext_vector_type(4))) half4;
typedef _Float16 __attribute__((ext_vector_type(8))) half8;

// ---------------- CSR build ----------------

__global__ __launch_bounds__(256) void hist_kernel(const int* __restrict__ dst,
                                                   int* __restrict__ deg) {
    int i = blockIdx.x * 256 + threadIdx.x;
    if (i < NEDGES) atomicAdd(&deg[dst[i]], 1);
}

__global__ __launch_bounds__(256) void bsum_kernel(const int* __restrict__ deg,
                                                   int* __restrict__ bsums) {
    int b = blockIdx.x, t = threadIdx.x;
    int base = b * 1024 + t * 4;
    int s = 0;
    #pragma unroll
    for (int e = 0; e < 4; ++e) { int i = base + e; if (i < NNODES) s += deg[i]; }
    #pragma unroll
    for (int o = 32; o; o >>= 1) s += __shfl_xor(s, o);
    __shared__ int ws[4];
    int lane = t & 63, wid = t >> 6;
    if (lane == 0) ws[wid] = s;
    __syncthreads();
    if (t == 0) bsums[b] = ws[0] + ws[1] + ws[2] + ws[3];
}

__global__ __launch_bounds__(256) void scan_write_kernel(const int* __restrict__ deg,
                                                         const int* __restrict__ bsums,
                                                         int* __restrict__ offs) {
    int b = blockIdx.x, t = threadIdx.x;
    int lane = t & 63, wid = t >> 6;
    int bv = (lane < b) ? bsums[lane] : 0;    // b <= NB-1 < 64
    #pragma unroll
    for (int o = 32; o; o >>= 1) bv += __shfl_xor(bv, o);  // block global offset
    int base = b * 1024 + t * 4;
    int v[4]; int tsum = 0;
    #pragma unroll
    for (int e = 0; e < 4; ++e) {
        int i = base + e;
        v[e] = (i < NNODES) ? deg[i] : 0;
        tsum += v[e];
    }
    int p = tsum;
    #pragma unroll
    for (int o = 1; o < 64; o <<= 1) { int u = __shfl_up(p, o); if (lane >= o) p += u; }
    __shared__ int ws[4];
    if (lane == 63) ws[wid] = p;
    __syncthreads();
    int woff = 0;
    for (int i = 0; i < wid; ++i) woff += ws[i];
    int run = bv + woff + p - tsum;           // exclusive prefix for this thread
    #pragma unroll
    for (int e = 0; e < 4; ++e) {
        int i = base + e;
        if (i < NNODES) { offs[i] = run; run += v[e]; }
    }
    if (b == 0 && t == 0) offs[NNODES] = NEDGES;
}

__global__ __launch_bounds__(256) void scatter_kernel(const int* __restrict__ src,
                                                      const int* __restrict__ dst,
                                                      const int* __restrict__ offs,
                                                      int* __restrict__ cursor,
                                                      int* __restrict__ ssorted) {
    int i = blockIdx.x * 256 + threadIdx.x;
    if (i < NEDGES) {
        int d = dst[i];
        int pos = offs[d] + atomicAdd(&cursor[d], 1);
        ssorted[pos] = src[i];
    }
}

// ---------------- weight transpose -> fp16 ----------------

__global__ __launch_bounds__(256) void convert_wt_kernel(const float* __restrict__ W,
                                                         _Float16* __restrict__ Wt,
                                                         int K, int N) {
    int idx = blockIdx.x * 256 + threadIdx.x;
    if (idx >= K * N) return;
    int k = idx / N, n = idx - k * N;
    Wt[n * K + k] = (_Float16)W[idx];
}

// ---------------- fp16 MFMA GEMM, LDS-free, 128x(BN) tile ----------------
// ELR=1 (BN=128): wave's 64 cols = one head -> el/er written HEAD-MAJOR
//   el[h*M+row] (consumed by fused spmm1 pre-pass).
// ELR=2 (BN=64): single head over all 64 cols; per-wn partial dot + 1KB LDS
//   combine -> el[row], er[row] (replaces elr2_kernel).

template <int BN, bool AFP16, int ELR>
__global__ __launch_bounds__(256) void gemm_f16_kernel(
        const float* __restrict__ Af, const _Float16* __restrict__ Ah,
        const _Float16* __restrict__ Bt,
        _Float16* __restrict__ C,
        const float* __restrict__ al, const float* __restrict__ ar,
        float* __restrict__ el, float* __restrict__ er,
        int M, int N) {
    constexpr int K = 256;
    constexpr int NT = BN / 32;       // 16-wide n-tiles per wave
    int t = threadIdx.x;
    int lane = t & 63, w = t >> 6;
    int wm = w >> 1, wn = w & 1;
    int lr = lane & 15, quad = lane >> 4;
    int m0 = blockIdx.y * 128, n0 = blockIdx.x * BN;

    f32x4 acc[4][NT];
    #pragma unroll
    for (int i = 0; i < 4; ++i)
        #pragma unroll
        for (int j = 0; j < NT; ++j) acc[i][j] = (f32x4){0.f, 0.f, 0.f, 0.f};

    int arow[4];
    #pragma unroll
    for (int i = 0; i < 4; ++i) {
        int r = m0 + wm * 64 + i * 16 + lr;
        arow[i] = (r < M) ? r : (M - 1);
    }
    int brow[NT];
    #pragma unroll
    for (int j = 0; j < NT; ++j) brow[j] = n0 + wn * NT * 16 + j * 16 + lr;

    #pragma unroll
    for (int kk = 0; kk < K; kk += 32) {
        half8 a[4], b[NT];
        if (AFP16) {
            #pragma unroll
            for (int i = 0; i < 4; ++i)
                a[i] = *(const half8*)(Ah + (size_t)arow[i] * K + kk + quad * 8);
        } else {
            #pragma unroll
            for (int i = 0; i < 4; ++i) {
                const float* ap = Af + (size_t)arow[i] * K + kk + quad * 8;
                float4 f0 = *(const float4*)ap;
                float4 f1 = *(const float4*)(ap + 4);
                a[i][0] = (_Float16)f0.x; a[i][1] = (_Float16)f0.y;
                a[i][2] = (_Float16)f0.z; a[i][3] = (_Float16)f0.w;
                a[i][4] = (_Float16)f1.x; a[i][5] = (_Float16)f1.y;
                a[i][6] = (_Float16)f1.z; a[i][7] = (_Float16)f1.w;
            }
        }
        #pragma unroll
        for (int j = 0; j < NT; ++j)
            b[j] = *(const half8*)(Bt + (size_t)brow[j] * K + kk + quad * 8);
        #pragma unroll
        for (int i = 0; i < 4; ++i)
            #pragma unroll
            for (int j = 0; j < NT; ++j)
                acc[i][j] = __builtin_amdgcn_mfma_f32_16x16x32_f16(a[i], b[j], acc[i][j], 0, 0, 0);
    }
    #pragma unroll
    for (int i = 0; i < 4; ++i) {
        #pragma unroll
        for (int r = 0; r < 4; ++r) {
            int row = m0 + wm * 64 + i * 16 + quad * 4 + r;
            if (row < M) {
                #pragma unroll
                for (int j = 0; j < NT; ++j)
                    C[(size_t)row * N + n0 + wn * NT * 16 + j * 16 + lr] =
                        (_Float16)acc[i][j][r];
            }
        }
    }
    if constexpr (ELR == 1) {
        // wave (wm,wn) covers head h = n0/64 + wn; write HEAD-MAJOR el[h*M+row]
        int h = n0 / 64 + wn;
        float alh[NT], arh[NT];
        #pragma unroll
        for (int j = 0; j < NT; ++j) {
            alh[j] = al[h * 64 + j * 16 + lr];
            arh[j] = ar[h * 64 + j * 16 + lr];
        }
        #pragma unroll
        for (int i = 0; i < 4; ++i) {
            #pragma unroll
            for (int r = 0; r < 4; ++r) {
                float pel = 0.f, per = 0.f;
                #pragma unroll
                for (int j = 0; j < NT; ++j) {
                    pel = fmaf(acc[i][j][r], alh[j], pel);
                    per = fmaf(acc[i][j][r], arh[j], per);
                }
                #pragma unroll
                for (int o = 1; o < 16; o <<= 1) {
                    pel += __shfl_xor(pel, o);
                    per += __shfl_xor(per, o);
                }
                if (lr == 0) {
                    int row = m0 + wm * 64 + i * 16 + quad * 4 + r;
                    if (row < M) {
                        el[(size_t)h * M + row] = pel;
                        er[(size_t)h * M + row] = per;
                    }
                }
            }
        }
    }
    if constexpr (ELR == 2) {
        // single head spanning all 64 cols; wn halves combine via LDS
        __shared__ float elbuf[128], erbuf[128];
        float alv[NT], arv[NT];
        #pragma unroll
        for (int j = 0; j < NT; ++j) {
            alv[j] = al[wn * NT * 16 + j * 16 + lr];
            arv[j] = ar[wn * NT * 16 + j * 16 + lr];
        }
        float pel_s[4][4], per_s[4][4];
        #pragma unroll
        for (int i = 0; i < 4; ++i) {
            #pragma unroll
            for (int r = 0; r < 4; ++r) {
                float pel = 0.f, per = 0.f;
                #pragma unroll
                for (int j = 0; j < NT; ++j) {
                    pel = fmaf(acc[i][j][r], alv[j], pel);
                    per = fmaf(acc[i][j][r], arv[j], per);
                }
                #pragma unroll
                for (int o = 1; o < 16; o <<= 1) {
                    pel += __shfl_xor(pel, o);
                    per += __shfl_xor(per, o);
                }
                pel_s[i][r] = pel; per_s[i][r] = per;
            }
        }
        if (wn == 1 && lr == 0) {
            #pragma unroll
            for (int i = 0; i < 4; ++i)
                #pragma unroll
                for (int r = 0; r < 4; ++r) {
                    int rl = wm * 64 + i * 16 + quad * 4 + r;
                    elbuf[rl] = pel_s[i][r];
                    erbuf[rl] = per_s[i][r];
                }
        }
        __syncthreads();
        if (wn == 0 && lr == 0) {
            #pragma unroll
            for (int i = 0; i < 4; ++i)
                #pragma unroll
                for (int r = 0; r < 4; ++r) {
                    int rl = wm * 64 + i * 16 + quad * 4 + r;
                    int row = m0 + rl;
                    if (row < M) {
                        el[row] = pel_s[i][r] + elbuf[rl];
                        er[row] = per_s[i][r] + erbuf[rl];
                    }
                }
        }
    }
}

// ---------------- fused softmax + weighted aggregation (layer 1) ----------
// Pre-pass: wave g computes head g's online (m,s) over the node's edges
// (el head-major [4][N], 4B broadcast-friendly gathers), LDS-broadcast
// m[4], rinv[4]. Main pass: x4-unrolled fp16 row gather with inline
// w = exp(lrelu(el+er)-m)*rinv. Numerically identical to alpha1+spmm1.

__global__ __launch_bounds__(256) void spmm1_kernel(const half4* __restrict__ feat,
                                                    const float* __restrict__ elh,  // [4][N]
                                                    const float* __restrict__ erh,  // [4][N]
                                                    const int* __restrict__ offs,
                                                    const int* __restrict__ ssorted,
                                                    _Float16* __restrict__ h1) {
    __shared__ float mbuf[4], rbuf[4];
    __shared__ float4 red[3][64];
    int n = blockIdx.x;
    int g = threadIdx.x >> 6, l = threadIdx.x & 63;
    int h = l >> 4;
    int start = offs[n], end = offs[n + 1];
    {   // pre-pass: wave g -> head g
        const float* elg = elh + (size_t)g * NNODES;
        float erg = erh[(size_t)g * NNODES + n];
        float m = -INFINITY, s = 0.f;
        for (int base = start; base + l < end; base += 64) {
            int sj = ssorted[base + l];
            float e = elg[sj] + erg;
            e = e > 0.f ? e : NEG_SLOPE * e;
            float nm = fmaxf(m, e);
            s = (m == nm ? s : s * __expf(m - nm)) + __expf(e - nm);
            m = nm;
        }
        #pragma unroll
        for (int o = 1; o < 64; o <<= 1) {
            float om = __shfl_xor(m, o), os = __shfl_xor(s, o);
            float nm = fmaxf(m, om);
            float sa = (m == nm) ? s : s * __expf(m - nm);
            float sb = (om == nm) ? os : os * __expf(om - nm);
            m = nm; s = sa + sb;
        }
        if (l == 0) { mbuf[g] = m; rbuf[g] = 1.f / s; }
    }
    __syncthreads();
    float mh = mbuf[h], rh = rbuf[h];
    float ern = erh[(size_t)h * NNODES + n];
    const float* elp = elh + (size_t)h * NNODES;
    float4 acc = {0.f, 0.f, 0.f, 0.f};
    int pos = start + g;
    for (; pos + 12 < end; pos += 16) {
        int s0 = ssorted[pos], s1 = ssorted[pos + 4],
            s2 = ssorted[pos + 8], s3 = ssorted[pos + 12];
        float e0 = elp[s0] + ern, e1 = elp[s1] + ern,
              e2 = elp[s2] + ern, e3 = elp[s3] + ern;
        half4 f0 = feat[(size_t)s0 * 64 + l];
        half4 f1 = feat[(size_t)s1 * 64 + l];
        half4 f2 = feat[(size_t)s2 * 64 + l];
        half4 f3 = feat[(size_t)s3 * 64 + l];
        e0 = e0 > 0.f ? e0 : NEG_SLOPE * e0;
        e1 = e1 > 0.f ? e1 : NEG_SLOPE * e1;
        e2 = e2 > 0.f ? e2 : NEG_SLOPE * e2;
        e3 = e3 > 0.f ? e3 : NEG_SLOPE * e3;
        float w0 = __expf(e0 - mh) * rh, w1 = __expf(e1 - mh) * rh;
        float w2 = __expf(e2 - mh) * rh, w3 = __expf(e3 - mh) * rh;
        acc.x = fmaf(w0, (float)f0[0], acc.x); acc.y = fmaf(w0, (float)f0[1], acc.y);
        acc.z = fmaf(w0, (float)f0[2], acc.z); acc.w = fmaf(w0, (float)f0[3], acc.w);
        acc.x = fmaf(w1, (float)f1[0], acc.x); acc.y = fmaf(w1, (float)f1[1], acc.y);
        acc.z = fmaf(w1, (float)f1[2], acc.z); acc.w = fmaf(w1, (float)f1[3], acc.w);
        acc.x = fmaf(w2, (float)f2[0], acc.x); acc.y = fmaf(w2, (float)f2[1], acc.y);
        acc.z = fmaf(w2, (float)f2[2], acc.z); acc.w = fmaf(w2, (float)f2[3], acc.w);
        acc.x = fmaf(w3, (float)f3[0], acc.x); acc.y = fmaf(w3, (float)f3[1], acc.y);
        acc.z = fmaf(w3, (float)f3[2], acc.z); acc.w = fmaf(w3, (float)f3[3], acc.w);
    }
    for (; pos < end; pos += 4) {
        int s = ssorted[pos];
        float e = elp[s] + ern;
        half4 f = feat[(size_t)s * 64 + l];
        e = e > 0.f ? e : NEG_SLOPE * e;
        float wgt = __expf(e - mh) * rh;
        acc.x = fmaf(wgt, (float)f[0], acc.x);
        acc.y = fmaf(wgt, (float)f[1], acc.y);
        acc.z = fmaf(wgt, (float)f[2], acc.z);
        acc.w = fmaf(wgt, (float)f[3], acc.w);
    }
    if (g) red[g - 1][l] = acc;
    __syncthreads();
    if (!g) {
        float4 b0 = red[0][l], b1 = red[1][l], b2 = red[2][l];
        acc.x += b0.x + b1.x + b2.x;
        acc.y += b0.y + b1.y + b2.y;
        acc.z += b0.z + b1.z + b2.z;
        acc.w += b0.w + b1.w + b2.w;
        acc.x = acc.x > 0.f ? acc.x : __expf(acc.x) - 1.f;   // ELU
        acc.y = acc.y > 0.f ? acc.y : __expf(acc.y) - 1.f;
        acc.z = acc.z > 0.f ? acc.z : __expf(acc.z) - 1.f;
        acc.w = acc.w > 0.f ? acc.w : __expf(acc.w) - 1.f;
        half4 hv = {(_Float16)acc.x, (_Float16)acc.y, (_Float16)acc.z, (_Float16)acc.w};
        *(half4*)&h1[(size_t)n * 256 + l * 4] = hv;
    }
}

// ---------------- fused softmax + weighted aggregation (layer 2) ----------
// Pre-pass: 256 threads stride edges for online (m,s); wave-reduce + LDS
// combine. Main: 16 subgroups of 16 lanes, x2 unroll, inline w.

__global__ __launch_bounds__(256) void spmm2_kernel(const half4* __restrict__ feat,
                                                    const float* __restrict__ el,
                                                    const float* __restrict__ er,
                                                    const int* __restrict__ offs,
                                                    const int* __restrict__ ssorted,
                                                    float4* __restrict__ out) {
    __shared__ float sm[4], ss[4];
    __shared__ float4 red[3][16];
    int n = blockIdx.x;
    int g = threadIdx.x >> 6, l = threadIdx.x & 63;
    int sub = l >> 4, li = l & 15;
    int start = offs[n], end = offs[n + 1];
    float ern = er[n];
    {   // pre-pass
        float m = -INFINITY, s = 0.f;
        for (int p = start + (int)threadIdx.x; p < end; p += 256) {
            int sj = ssorted[p];
            float e = el[sj] + ern;
            e = e > 0.f ? e : NEG_SLOPE * e;
            float nm = fmaxf(m, e);
            s = (m == nm ? s : s * __expf(m - nm)) + __expf(e - nm);
            m = nm;
        }
        #pragma unroll
        for (int o = 1; o < 64; o <<= 1) {
            float om = __shfl_xor(m, o), os = __shfl_xor(s, o);
            float nm = fmaxf(m, om);
            float sa = (m == nm) ? s : s * __expf(m - nm);
            float sb = (om == nm) ? os : os * __expf(om - nm);
            m = nm; s = sa + sb;
        }
        if (l == 0) { sm[g] = m; ss[g] = s; }
    }
    __syncthreads();
    if (threadIdx.x == 0) {
        float M = fmaxf(fmaxf(sm[0], sm[1]), fmaxf(sm[2], sm[3]));
        float S = 0.f;
        #pragma unroll
        for (int i = 0; i < 4; ++i)
            S += ss[i] * ((sm[i] == M) ? 1.f : __expf(sm[i] - M));
        sm[0] = M; ss[0] = 1.f / S;
    }
    __syncthreads();
    float mh = sm[0], rh = ss[0];
    float4 acc = {0.f, 0.f, 0.f, 0.f};
    int pos = start + g * 4 + sub;
    for (; pos + 16 < end; pos += 32) {
        int s0 = ssorted[pos], s1 = ssorted[pos + 16];
        float e0 = el[s0] + ern, e1 = el[s1] + ern;
        half4 f0 = feat[(size_t)s0 * 16 + li];
        half4 f1 = feat[(size_t)s1 * 16 + li];
        e0 = e0 > 0.f ? e0 : NEG_SLOPE * e0;
        e1 = e1 > 0.f ? e1 : NEG_SLOPE * e1;
        float w0 = __expf(e0 - mh) * rh, w1 = __expf(e1 - mh) * rh;
        acc.x = fmaf(w0, (float)f0[0], acc.x); acc.y = fmaf(w0, (float)f0[1], acc.y);
        acc.z = fmaf(w0, (float)f0[2], acc.z); acc.w = fmaf(w0, (float)f0[3], acc.w);
        acc.x = fmaf(w1, (float)f1[0], acc.x); acc.y = fmaf(w1, (float)f1[1], acc.y);
        acc.z = fmaf(w1, (float)f1[2], acc.z); acc.w = fmaf(w1, (float)f1[3], acc.w);
    }
    for (; pos < end; pos += 16) {
        int s = ssorted[pos];
        float e = el[s] + ern;
        half4 f = feat[(size_t)s * 16 + li];
        e = e > 0.f ? e : NEG_SLOPE * e;
        float wgt = __expf(e - mh) * rh;
        acc.x = fmaf(wgt, (float)f[0], acc.x);
        acc.y = fmaf(wgt, (float)f[1], acc.y);
        acc.z = fmaf(wgt, (float)f[2], acc.z);
        acc.w = fmaf(wgt, (float)f[3], acc.w);
    }
    #pragma unroll
    for (int o = 16; o < 64; o <<= 1) {
        acc.x += __shfl_xor(acc.x, o);
        acc.y += __shfl_xor(acc.y, o);
        acc.z += __shfl_xor(acc.z, o);
        acc.w += __shfl_xor(acc.w, o);
    }
    if (g && sub == 0) red[g - 1][li] = acc;
    __syncthreads();
    if (!g && sub == 0) {
        float4 b0 = red[0][li], b1 = red[1][li], b2 = red[2][li];
        acc.x += b0.x + b1.x + b2.x;
        acc.y += b0.y + b1.y + b2.y;
        acc.z += b0.z + b1.z + b2.z;
        acc.w += b0.w + b1.w + b2.w;
        out[(size_t)n * 16 + li] = acc;
    }
}

// ---------------- launch ----------------

extern "C" void kernel_launch(void* const* d_in, const int* in_sizes, int n_in,
                              void* d_out, int out_size, void* d_ws, size_t ws_size,
                              hipStream_t stream) {
    const float* x   = (const float*)d_in[0];
    const int*   src = (const int*)d_in[1];
    const int*   dst = (const int*)d_in[2];
    const float* W1  = (const float*)d_in[3];
    const float* al1 = (const float*)d_in[4];
    const float* ar1 = (const float*)d_in[5];
    const float* W2  = (const float*)d_in[6];
    const float* al2 = (const float*)d_in[7];
    const float* ar2 = (const float*)d_in[8];
    float* out = (float*)d_out;

    char* ws = (char*)d_ws;
    size_t off = 0;
    auto alloc = [&](size_t bytes) -> void* {
        void* p = ws + off;
        off += (bytes + 255) & ~(size_t)255;
        return p;
    };
    _Float16* feat1 = (_Float16*)alloc((size_t)NNODES * 256 * 2);   // 25.6 MB
    _Float16* h1    = (_Float16*)alloc((size_t)NNODES * 256 * 2);   // 25.6 MB
    _Float16* W1t   = (_Float16*)alloc((size_t)256 * 256 * 2);
    _Float16* W2t   = (_Float16*)alloc((size_t)64 * 256 * 2);
    float* el1    = (float*)alloc((size_t)HEADS * NNODES * 4);      // head-major [4][N]
    float* er1    = (float*)alloc((size_t)HEADS * NNODES * 4);
    float* el2    = (float*)alloc((size_t)NNODES * 4);
    float* er2    = (float*)alloc((size_t)NNODES * 4);
    int* deg      = (int*)alloc((size_t)NNODES * 4);
    int* cursor   = (int*)alloc((size_t)NNODES * 4);
    int* offs     = (int*)alloc((size_t)(NNODES + 1) * 4);
    int* bsums    = (int*)alloc((size_t)NB * 4);
    int* ssorted  = (int*)alloc((size_t)NEDGES * 4);
    _Float16* feat2 = feat1;   // feat1 dead after spmm1; reuse for layer 2

    // --- CSR build ---
    hipMemsetAsync(deg, 0, (size_t)NNODES * 4, stream);
    hipMemsetAsync(cursor, 0, (size_t)NNODES * 4, stream);
    hist_kernel<<<(NEDGES + 255) / 256, 256, 0, stream>>>(dst, deg);
    bsum_kernel<<<NB, 256, 0, stream>>>(deg, bsums);
    scan_write_kernel<<<NB, 256, 0, stream>>>(deg, bsums, offs);
    scatter_kernel<<<(NEDGES + 255) / 256, 256, 0, stream>>>(src, dst, offs, cursor, ssorted);

    // --- weight conversions ---
    convert_wt_kernel<<<(256 * 256 + 255) / 256, 256, 0, stream>>>(W1, W1t, 256, 256);
    convert_wt_kernel<<<(256 * 64 + 255) / 256, 256, 0, stream>>>(W2, W2t, 256, 64);

    // --- Layer 1: fp16 GEMM + fused head-major el/er; fused-softmax SpMM ---
    gemm_f16_kernel<128, false, 1><<<dim3(256 / 128, (NNODES + 127) / 128), 256, 0, stream>>>(
        x, nullptr, W1t, feat1, al1, ar1, el1, er1, NNODES, 256);
    spmm1_kernel<<<NNODES, 256, 0, stream>>>(
        (const half4*)feat1, el1, er1, offs, ssorted, h1);

    // --- Layer 2: fp16 GEMM + fused single-head el/er; fused-softmax SpMM ---
    gemm_f16_kernel<64, true, 2><<<dim3(64 / 64, (NNODES + 127) / 128), 256, 0, stream>>>(
        nullptr, h1, W2t, feat2, al2, ar2, el2, er2, NNODES, 64);
    spmm2_kernel<<<NNODES, 256, 0, stream>>>(
        (const half4*)feat2, el2, er2, offs, ssorted, (float4*)out);
}

// Round 11
// 437.609 us; speedup vs baseline: 1.0113x; 1.0113x over previous
//
#include <hip/hip_runtime.h>
#include <math.h>

#define NNODES 50000
#define NEDGES 800000
#define INDIM 256
#define HID 64
#define HEADS 4
#define OUTDIM 64
#define NEG_SLOPE 0.2f
#define NB ((NNODES + 1023) / 1024)   // 49 scan blocks

typedef __attribute__((ext_vector_type(4))) float f32x4;
typedef _Float16 __attribute__((ext_vector_type(4))) half4;
typedef _Float16 __attribute__((ext_vector_type(8))) half8;

// ---------------- CSR build ----------------

__global__ __launch_bounds__(256) void hist_kernel(const int* __restrict__ dst,
                                                   int* __restrict__ deg) {
    int i = blockIdx.x * 256 + threadIdx.x;
    if (i < NEDGES) atomicAdd(&deg[dst[i]], 1);
}

__global__ __launch_bounds__(256) void bsum_kernel(const int* __restrict__ deg,
                                                   int* __restrict__ bsums) {
    int b = blockIdx.x, t = threadIdx.x;
    int base = b * 1024 + t * 4;
    int s = 0;
    #pragma unroll
    for (int e = 0; e < 4; ++e) { int i = base + e; if (i < NNODES) s += deg[i]; }
    #pragma unroll
    for (int o = 32; o; o >>= 1) s += __shfl_xor(s, o);
    __shared__ int ws[4];
    int lane = t & 63, wid = t >> 6;
    if (lane == 0) ws[wid] = s;
    __syncthreads();
    if (t == 0) bsums[b] = ws[0] + ws[1] + ws[2] + ws[3];
}

__global__ __launch_bounds__(256) void scan_write_kernel(const int* __restrict__ deg,
                                                         const int* __restrict__ bsums,
                                                         int* __restrict__ offs) {
    int b = blockIdx.x, t = threadIdx.x;
    int lane = t & 63, wid = t >> 6;
    int bv = (lane < b) ? bsums[lane] : 0;    // b <= NB-1 < 64
    #pragma unroll
    for (int o = 32; o; o >>= 1) bv += __shfl_xor(bv, o);  // block global offset
    int base = b * 1024 + t * 4;
    int v[4]; int tsum = 0;
    #pragma unroll
    for (int e = 0; e < 4; ++e) {
        int i = base + e;
        v[e] = (i < NNODES) ? deg[i] : 0;
        tsum += v[e];
    }
    int p = tsum;
    #pragma unroll
    for (int o = 1; o < 64; o <<= 1) { int u = __shfl_up(p, o); if (lane >= o) p += u; }
    __shared__ int ws[4];
    if (lane == 63) ws[wid] = p;
    __syncthreads();
    int woff = 0;
    for (int i = 0; i < wid; ++i) woff += ws[i];
    int run = bv + woff + p - tsum;           // exclusive prefix for this thread
    #pragma unroll
    for (int e = 0; e < 4; ++e) {
        int i = base + e;
        if (i < NNODES) { offs[i] = run; run += v[e]; }
    }
    if (b == 0 && t == 0) offs[NNODES] = NEDGES;
}

__global__ __launch_bounds__(256) void scatter_kernel(const int* __restrict__ src,
                                                      const int* __restrict__ dst,
                                                      const int* __restrict__ offs,
                                                      int* __restrict__ cursor,
                                                      int* __restrict__ ssorted) {
    int i = blockIdx.x * 256 + threadIdx.x;
    if (i < NEDGES) {
        int d = dst[i];
        int pos = offs[d] + atomicAdd(&cursor[d], 1);
        ssorted[pos] = src[i];
    }
}

// ---------------- weight transpose -> fp16 ----------------

__global__ __launch_bounds__(256) void convert_wt_kernel(const float* __restrict__ W,
                                                         _Float16* __restrict__ Wt,
                                                         int K, int N) {
    int idx = blockIdx.x * 256 + threadIdx.x;
    if (idx >= K * N) return;
    int k = idx / N, n = idx - k * N;
    Wt[n * K + k] = (_Float16)W[idx];
}

// ---------------- fp16 MFMA GEMM, LDS-free, 128x(BN) tile ----------------
// ELR=1 (BN=128): wave's 64 cols = one head -> el/er written HEAD-MAJOR
//   el[h*M+row] (consumed by fused spmm1 pre-pass).
// ELR=2 (BN=64): single head over all 64 cols; per-wn partial dot + 1KB LDS
//   combine -> el[row], er[row].

template <int BN, bool AFP16, int ELR>
__global__ __launch_bounds__(256) void gemm_f16_kernel(
        const float* __restrict__ Af, const _Float16* __restrict__ Ah,
        const _Float16* __restrict__ Bt,
        _Float16* __restrict__ C,
        const float* __restrict__ al, const float* __restrict__ ar,
        float* __restrict__ el, float* __restrict__ er,
        int M, int N) {
    constexpr int K = 256;
    constexpr int NT = BN / 32;       // 16-wide n-tiles per wave
    int t = threadIdx.x;
    int lane = t & 63, w = t >> 6;
    int wm = w >> 1, wn = w & 1;
    int lr = lane & 15, quad = lane >> 4;
    int m0 = blockIdx.y * 128, n0 = blockIdx.x * BN;

    f32x4 acc[4][NT];
    #pragma unroll
    for (int i = 0; i < 4; ++i)
        #pragma unroll
        for (int j = 0; j < NT; ++j) acc[i][j] = (f32x4){0.f, 0.f, 0.f, 0.f};

    int arow[4];
    #pragma unroll
    for (int i = 0; i < 4; ++i) {
        int r = m0 + wm * 64 + i * 16 + lr;
        arow[i] = (r < M) ? r : (M - 1);
    }
    int brow[NT];
    #pragma unroll
    for (int j = 0; j < NT; ++j) brow[j] = n0 + wn * NT * 16 + j * 16 + lr;

    #pragma unroll
    for (int kk = 0; kk < K; kk += 32) {
        half8 a[4], b[NT];
        if (AFP16) {
            #pragma unroll
            for (int i = 0; i < 4; ++i)
                a[i] = *(const half8*)(Ah + (size_t)arow[i] * K + kk + quad * 8);
        } else {
            #pragma unroll
            for (int i = 0; i < 4; ++i) {
                const float* ap = Af + (size_t)arow[i] * K + kk + quad * 8;
                float4 f0 = *(const float4*)ap;
                float4 f1 = *(const float4*)(ap + 4);
                a[i][0] = (_Float16)f0.x; a[i][1] = (_Float16)f0.y;
                a[i][2] = (_Float16)f0.z; a[i][3] = (_Float16)f0.w;
                a[i][4] = (_Float16)f1.x; a[i][5] = (_Float16)f1.y;
                a[i][6] = (_Float16)f1.z; a[i][7] = (_Float16)f1.w;
            }
        }
        #pragma unroll
        for (int j = 0; j < NT; ++j)
            b[j] = *(const half8*)(Bt + (size_t)brow[j] * K + kk + quad * 8);
        #pragma unroll
        for (int i = 0; i < 4; ++i)
            #pragma unroll
            for (int j = 0; j < NT; ++j)
                acc[i][j] = __builtin_amdgcn_mfma_f32_16x16x32_f16(a[i], b[j], acc[i][j], 0, 0, 0);
    }
    #pragma unroll
    for (int i = 0; i < 4; ++i) {
        #pragma unroll
        for (int r = 0; r < 4; ++r) {
            int row = m0 + wm * 64 + i * 16 + quad * 4 + r;
            if (row < M) {
                #pragma unroll
                for (int j = 0; j < NT; ++j)
                    C[(size_t)row * N + n0 + wn * NT * 16 + j * 16 + lr] =
                        (_Float16)acc[i][j][r];
            }
        }
    }
    if constexpr (ELR == 1) {
        int h = n0 / 64 + wn;
        float alh[NT], arh[NT];
        #pragma unroll
        for (int j = 0; j < NT; ++j) {
            alh[j] = al[h * 64 + j * 16 + lr];
            arh[j] = ar[h * 64 + j * 16 + lr];
        }
        #pragma unroll
        for (int i = 0; i < 4; ++i) {
            #pragma unroll
            for (int r = 0; r < 4; ++r) {
                float pel = 0.f, per = 0.f;
                #pragma unroll
                for (int j = 0; j < NT; ++j) {
                    pel = fmaf(acc[i][j][r], alh[j], pel);
                    per = fmaf(acc[i][j][r], arh[j], per);
                }
                #pragma unroll
                for (int o = 1; o < 16; o <<= 1) {
                    pel += __shfl_xor(pel, o);
                    per += __shfl_xor(per, o);
                }
                if (lr == 0) {
                    int row = m0 + wm * 64 + i * 16 + quad * 4 + r;
                    if (row < M) {
                        el[(size_t)h * M + row] = pel;
                        er[(size_t)h * M + row] = per;
                    }
                }
            }
        }
    }
    if constexpr (ELR == 2) {
        __shared__ float elbuf[128], erbuf[128];
        float alv[NT], arv[NT];
        #pragma unroll
        for (int j = 0; j < NT; ++j) {
            alv[j] = al[wn * NT * 16 + j * 16 + lr];
            arv[j] = ar[wn * NT * 16 + j * 16 + lr];
        }
        float pel_s[4][4], per_s[4][4];
        #pragma unroll
        for (int i = 0; i < 4; ++i) {
            #pragma unroll
            for (int r = 0; r < 4; ++r) {
                float pel = 0.f, per = 0.f;
                #pragma unroll
                for (int j = 0; j < NT; ++j) {
                    pel = fmaf(acc[i][j][r], alv[j], pel);
                    per = fmaf(acc[i][j][r], arv[j], per);
                }
                #pragma unroll
                for (int o = 1; o < 16; o <<= 1) {
                    pel += __shfl_xor(pel, o);
                    per += __shfl_xor(per, o);
                }
                pel_s[i][r] = pel; per_s[i][r] = per;
            }
        }
        if (wn == 1 && lr == 0) {
            #pragma unroll
            for (int i = 0; i < 4; ++i)
                #pragma unroll
                for (int r = 0; r < 4; ++r) {
                    int rl = wm * 64 + i * 16 + quad * 4 + r;
                    elbuf[rl] = pel_s[i][r];
                    erbuf[rl] = per_s[i][r];
                }
        }
        __syncthreads();
        if (wn == 0 && lr == 0) {
            #pragma unroll
            for (int i = 0; i < 4; ++i)
                #pragma unroll
                for (int r = 0; r < 4; ++r) {
                    int rl = wm * 64 + i * 16 + quad * 4 + r;
                    int row = m0 + rl;
                    if (row < M) {
                        el[row] = pel_s[i][r] + elbuf[rl];
                        er[row] = per_s[i][r] + erbuf[rl];
                    }
                }
        }
    }
}

// ---------------- fused softmax + weighted aggregation (layer 1) ----------
// R10 post-mortem: inline per-lane w computation = 64x redundant exp ->
// VALUBusy 92%. R11: stage w through LDS per 64-edge chunk. Wave g (head g)
// computes w lane-parallel (ONE exp per edge per head), writes wbuf[4][64] +
// sidx[64]; gather then reads w from LDS (broadcast, 4 addrs/wave).

__global__ __launch_bounds__(256) void spmm1_kernel(const half4* __restrict__ feat,
                                                    const float* __restrict__ elh,  // [4][N]
                                                    const float* __restrict__ erh,  // [4][N]
                                                    const int* __restrict__ offs,
                                                    const int* __restrict__ ssorted,
                                                    _Float16* __restrict__ h1) {
    __shared__ float mbuf[4], rbuf[4];
    __shared__ float wbuf[4][64];
    __shared__ int sidx[64];
    __shared__ float4 red[3][64];
    int n = blockIdx.x;
    int g = threadIdx.x >> 6, l = threadIdx.x & 63;
    int h = l >> 4;
    int start = offs[n], end = offs[n + 1];
    const float* elg = elh + (size_t)g * NNODES;
    float erg = erh[(size_t)g * NNODES + n];
    {   // pre-pass: wave g -> head g online (m,s)
        float m = -INFINITY, s = 0.f;
        for (int base = start; base + l < end; base += 64) {
            int sj = ssorted[base + l];
            float e = elg[sj] + erg;
            e = e > 0.f ? e : NEG_SLOPE * e;
            float nm = fmaxf(m, e);
            s = (m == nm ? s : s * __expf(m - nm)) + __expf(e - nm);
            m = nm;
        }
        #pragma unroll
        for (int o = 1; o < 64; o <<= 1) {
            float om = __shfl_xor(m, o), os = __shfl_xor(s, o);
            float nm = fmaxf(m, om);
            float sa = (m == nm) ? s : s * __expf(m - nm);
            float sb = (om == nm) ? os : os * __expf(om - nm);
            m = nm; s = sa + sb;
        }
        if (l == 0) { mbuf[g] = m; rbuf[g] = 1.f / s; }
    }
    __syncthreads();
    float mg = mbuf[g], rg = rbuf[g];   // staging constants for head g
    float4 acc = {0.f, 0.f, 0.f, 0.f};
    for (int base = start; base < end; base += 64) {
        int cnt = min(64, end - base);
        if (l < cnt) {   // stage w lane-parallel: one exp per edge per head
            int sj = ssorted[base + l];
            float e = elg[sj] + erg;
            e = e > 0.f ? e : NEG_SLOPE * e;
            wbuf[g][l] = __expf(e - mg) * rg;
            if (g == 0) sidx[l] = sj;
        }
        __syncthreads();
        int j = g;
        for (; j + 12 < cnt; j += 16) {
            int s0 = sidx[j], s1 = sidx[j + 4], s2 = sidx[j + 8], s3 = sidx[j + 12];
            float w0 = wbuf[h][j], w1 = wbuf[h][j + 4],
                  w2 = wbuf[h][j + 8], w3 = wbuf[h][j + 12];
            half4 f0 = feat[(size_t)s0 * 64 + l];
            half4 f1 = feat[(size_t)s1 * 64 + l];
            half4 f2 = feat[(size_t)s2 * 64 + l];
            half4 f3 = feat[(size_t)s3 * 64 + l];
            acc.x = fmaf(w0, (float)f0[0], acc.x); acc.y = fmaf(w0, (float)f0[1], acc.y);
            acc.z = fmaf(w0, (float)f0[2], acc.z); acc.w = fmaf(w0, (float)f0[3], acc.w);
            acc.x = fmaf(w1, (float)f1[0], acc.x); acc.y = fmaf(w1, (float)f1[1], acc.y);
            acc.z = fmaf(w1, (float)f1[2], acc.z); acc.w = fmaf(w1, (float)f1[3], acc.w);
            acc.x = fmaf(w2, (float)f2[0], acc.x); acc.y = fmaf(w2, (float)f2[1], acc.y);
            acc.z = fmaf(w2, (float)f2[2], acc.z); acc.w = fmaf(w2, (float)f2[3], acc.w);
            acc.x = fmaf(w3, (float)f3[0], acc.x); acc.y = fmaf(w3, (float)f3[1], acc.y);
            acc.z = fmaf(w3, (float)f3[2], acc.z); acc.w = fmaf(w3, (float)f3[3], acc.w);
        }
        for (; j < cnt; j += 4) {
            int s = sidx[j];
            float wgt = wbuf[h][j];
            half4 f = feat[(size_t)s * 64 + l];
            acc.x = fmaf(wgt, (float)f[0], acc.x);
            acc.y = fmaf(wgt, (float)f[1], acc.y);
            acc.z = fmaf(wgt, (float)f[2], acc.z);
            acc.w = fmaf(wgt, (float)f[3], acc.w);
        }
        __syncthreads();   // protect wbuf/sidx before next chunk
    }
    if (g) red[g - 1][l] = acc;
    __syncthreads();
    if (!g) {
        float4 b0 = red[0][l], b1 = red[1][l], b2 = red[2][l];
        acc.x += b0.x + b1.x + b2.x;
        acc.y += b0.y + b1.y + b2.y;
        acc.z += b0.z + b1.z + b2.z;
        acc.w += b0.w + b1.w + b2.w;
        acc.x = acc.x > 0.f ? acc.x : __expf(acc.x) - 1.f;   // ELU
        acc.y = acc.y > 0.f ? acc.y : __expf(acc.y) - 1.f;
        acc.z = acc.z > 0.f ? acc.z : __expf(acc.z) - 1.f;
        acc.w = acc.w > 0.f ? acc.w : __expf(acc.w) - 1.f;
        half4 hv = {(_Float16)acc.x, (_Float16)acc.y, (_Float16)acc.z, (_Float16)acc.w};
        *(half4*)&h1[(size_t)n * 256 + l * 4] = hv;
    }
}

// ---------------- fused softmax + weighted aggregation (layer 2) ----------
// Same LDS w-staging, 256-edge chunks, block-wide.

__global__ __launch_bounds__(256) void spmm2_kernel(const half4* __restrict__ feat,
                                                    const float* __restrict__ el,
                                                    const float* __restrict__ er,
                                                    const int* __restrict__ offs,
                                                    const int* __restrict__ ssorted,
                                                    float4* __restrict__ out) {
    __shared__ float sm[4], ss[4];
    __shared__ float wbuf[256];
    __shared__ int sidx[256];
    __shared__ float4 red[3][16];
    int n = blockIdx.x;
    int t = threadIdx.x;
    int g = t >> 6, l = t & 63;
    int sub = l >> 4, li = l & 15;
    int start = offs[n], end = offs[n + 1];
    float ern = er[n];
    {   // pre-pass
        float m = -INFINITY, s = 0.f;
        for (int p = start + t; p < end; p += 256) {
            int sj = ssorted[p];
            float e = el[sj] + ern;
            e = e > 0.f ? e : NEG_SLOPE * e;
            float nm = fmaxf(m, e);
            s = (m == nm ? s : s * __expf(m - nm)) + __expf(e - nm);
            m = nm;
        }
        #pragma unroll
        for (int o = 1; o < 64; o <<= 1) {
            float om = __shfl_xor(m, o), os = __shfl_xor(s, o);
            float nm = fmaxf(m, om);
            float sa = (m == nm) ? s : s * __expf(m - nm);
            float sb = (om == nm) ? os : os * __expf(om - nm);
            m = nm; s = sa + sb;
        }
        if (l == 0) { sm[g] = m; ss[g] = s; }
    }
    __syncthreads();
    if (t == 0) {
        float M = fmaxf(fmaxf(sm[0], sm[1]), fmaxf(sm[2], sm[3]));
        float S = 0.f;
        #pragma unroll
        for (int i = 0; i < 4; ++i)
            S += ss[i] * ((sm[i] == M) ? 1.f : __expf(sm[i] - M));
        sm[0] = M; ss[0] = 1.f / S;
    }
    __syncthreads();
    float mh = sm[0], rh = ss[0];
    float4 acc = {0.f, 0.f, 0.f, 0.f};
    for (int base = start; base < end; base += 256) {
        int cnt = min(256, end - base);
        if (t < cnt) {   // stage w: one exp per edge
            int sj = ssorted[base + t];
            float e = el[sj] + ern;
            e = e > 0.f ? e : NEG_SLOPE * e;
            wbuf[t] = __expf(e - mh) * rh;
            sidx[t] = sj;
        }
        __syncthreads();
        int j = g * 4 + sub;
        for (; j + 16 < cnt; j += 32) {
            int s0 = sidx[j], s1 = sidx[j + 16];
            float w0 = wbuf[j], w1 = wbuf[j + 16];
            half4 f0 = feat[(size_t)s0 * 16 + li];
            half4 f1 = feat[(size_t)s1 * 16 + li];
            acc.x = fmaf(w0, (float)f0[0], acc.x); acc.y = fmaf(w0, (float)f0[1], acc.y);
            acc.z = fmaf(w0, (float)f0[2], acc.z); acc.w = fmaf(w0, (float)f0[3], acc.w);
            acc.x = fmaf(w1, (float)f1[0], acc.x); acc.y = fmaf(w1, (float)f1[1], acc.y);
            acc.z = fmaf(w1, (float)f1[2], acc.z); acc.w = fmaf(w1, (float)f1[3], acc.w);
        }
        for (; j < cnt; j += 16) {
            int s = sidx[j];
            float wgt = wbuf[j];
            half4 f = feat[(size_t)s * 16 + li];
            acc.x = fmaf(wgt, (float)f[0], acc.x);
            acc.y = fmaf(wgt, (float)f[1], acc.y);
            acc.z = fmaf(wgt, (float)f[2], acc.z);
            acc.w = fmaf(wgt, (float)f[3], acc.w);
        }
        __syncthreads();
    }
    #pragma unroll
    for (int o = 16; o < 64; o <<= 1) {
        acc.x += __shfl_xor(acc.x, o);
        acc.y += __shfl_xor(acc.y, o);
        acc.z += __shfl_xor(acc.z, o);
        acc.w += __shfl_xor(acc.w, o);
    }
    if (g && sub == 0) red[g - 1][li] = acc;
    __syncthreads();
    if (!g && sub == 0) {
        float4 b0 = red[0][li], b1 = red[1][li], b2 = red[2][li];
        acc.x += b0.x + b1.x + b2.x;
        acc.y += b0.y + b1.y + b2.y;
        acc.z += b0.z + b1.z + b2.z;
        acc.w += b0.w + b1.w + b2.w;
        out[(size_t)n * 16 + li] = acc;
    }
}

// ---------------- launch ----------------

extern "C" void kernel_launch(void* const* d_in, const int* in_sizes, int n_in,
                              void* d_out, int out_size, void* d_ws, size_t ws_size,
                              hipStream_t stream) {
    const float* x   = (const float*)d_in[0];
    const int*   src = (const int*)d_in[1];
    const int*   dst = (const int*)d_in[2];
    const float* W1  = (const float*)d_in[3];
    const float* al1 = (const float*)d_in[4];
    const float* ar1 = (const float*)d_in[5];
    const float* W2  = (const float*)d_in[6];
    const float* al2 = (const float*)d_in[7];
    const float* ar2 = (const float*)d_in[8];
    float* out = (float*)d_out;

    char* ws = (char*)d_ws;
    size_t off = 0;
    auto alloc = [&](size_t bytes) -> void* {
        void* p = ws + off;
        off += (bytes + 255) & ~(size_t)255;
        return p;
    };
    _Float16* feat1 = (_Float16*)alloc((size_t)NNODES * 256 * 2);   // 25.6 MB
    _Float16* h1    = (_Float16*)alloc((size_t)NNODES * 256 * 2);   // 25.6 MB
    _Float16* W1t   = (_Float16*)alloc((size_t)256 * 256 * 2);
    _Float16* W2t   = (_Float16*)alloc((size_t)64 * 256 * 2);
    float* el1    = (float*)alloc((size_t)HEADS * NNODES * 4);      // head-major [4][N]
    float* er1    = (float*)alloc((size_t)HEADS * NNODES * 4);
    float* el2    = (float*)alloc((size_t)NNODES * 4);
    float* er2    = (float*)alloc((size_t)NNODES * 4);
    int* deg      = (int*)alloc((size_t)NNODES * 4);
    int* cursor   = (int*)alloc((size_t)NNODES * 4);
    int* offs     = (int*)alloc((size_t)(NNODES + 1) * 4);
    int* bsums    = (int*)alloc((size_t)NB * 4);
    int* ssorted  = (int*)alloc((size_t)NEDGES * 4);
    _Float16* feat2 = feat1;   // feat1 dead after spmm1; reuse for layer 2

    // --- CSR build ---
    hipMemsetAsync(deg, 0, (size_t)NNODES * 4, stream);
    hipMemsetAsync(cursor, 0, (size_t)NNODES * 4, stream);
    hist_kernel<<<(NEDGES + 255) / 256, 256, 0, stream>>>(dst, deg);
    bsum_kernel<<<NB, 256, 0, stream>>>(deg, bsums);
    scan_write_kernel<<<NB, 256, 0, stream>>>(deg, bsums, offs);
    scatter_kernel<<<(NEDGES + 255) / 256, 256, 0, stream>>>(src, dst, offs, cursor, ssorted);

    // --- weight conversions ---
    convert_wt_kernel<<<(256 * 256 + 255) / 256, 256, 0, stream>>>(W1, W1t, 256, 256);
    convert_wt_kernel<<<(256 * 64 + 255) / 256, 256, 0, stream>>>(W2, W2t, 256, 64);

    // --- Layer 1: fp16 GEMM + fused head-major el/er; fused-softmax SpMM ---
    gemm_f16_kernel<128, false, 1><<<dim3(256 / 128, (NNODES + 127) / 128), 256, 0, stream>>>(
        x, nullptr, W1t, feat1, al1, ar1, el1, er1, NNODES, 256);
    spmm1_kernel<<<NNODES, 256, 0, stream>>>(
        (const half4*)feat1, el1, er1, offs, ssorted, h1);

    // --- Layer 2: fp16 GEMM + fused single-head el/er; fused-softmax SpMM ---
    gemm_f16_kernel<64, true, 2><<<dim3(64 / 64, (NNODES + 127) / 128), 256, 0, stream>>>(
        nullptr, h1, W2t, feat2, al2, ar2, el2, er2, NNODES, 64);
    spmm2_kernel<<<NNODES, 256, 0, stream>>>(
        (const half4*)feat2, el2, er2, offs, ssorted, (float4*)out);
}